// Round 1
// baseline (368.223 us; speedup 1.0000x reference)
//
#include <hip/hip_runtime.h>

// Problem: x[32,8,512,512] fp32 -> out[32,512,32] fp32.
// Each element (r,w) contributes to exactly one shell per corner:
//   TL bin max(r,w), TR bin max(r,511-w), BL bin max(511-r,w), BR bin max(511-r,511-w).
// Single streaming pass (268 MB) => memory-bound, roofline ~43 us.
//
// Identities (verified on 2x2 example), with p(j)=prefix of row r, T=row total,
// colA[r]=col-r cumsum through row r, colB[r]=same at col 511-r, total[c]=col sums:
//   TL[r]     = p(r-1)   + colA[r]
//   TR[r]     = T - p(511-r) + colB[r]
//   BL[511-r] = p(511-r) + total[511-r] - colB[r]
//   BR[511-r] = T - p(r-1) + total[r]   - colA[r]
// Row-strip decomposition: row sums are exact per block (block owns full rows);
// column sums need only a cross-strip prefix of per-strip column totals (kernel 2).

#define PLANES 256   // B*C = 32*8
#define WW     512
#define HH     512
#define JBLK   8     // row-strips per plane
#define RPB    64    // rows per block = HH / JBLK

// Full 64-lane sum via DPP (VALU pipe, no LDS traffic). Result in lane 63.
__device__ __forceinline__ float wave_sum64(float v) {
  v += __int_as_float(__builtin_amdgcn_update_dpp(0, __float_as_int(v), 0x111, 0xf, 0xf, true)); // row_shr:1
  v += __int_as_float(__builtin_amdgcn_update_dpp(0, __float_as_int(v), 0x112, 0xf, 0xf, true)); // row_shr:2
  v += __int_as_float(__builtin_amdgcn_update_dpp(0, __float_as_int(v), 0x114, 0xf, 0xf, true)); // row_shr:4
  v += __int_as_float(__builtin_amdgcn_update_dpp(0, __float_as_int(v), 0x118, 0xf, 0xf, true)); // row_shr:8
  v += __int_as_float(__builtin_amdgcn_update_dpp(0, __float_as_int(v), 0x142, 0xf, 0xf, true)); // row_bcast:15
  v += __int_as_float(__builtin_amdgcn_update_dpp(0, __float_as_int(v), 0x143, 0xf, 0xf, true)); // row_bcast:31
  return v;
}

// Kernel 1: one block per (plane, row-strip). 128 threads (2 waves); lane owns
// 4 contiguous cols via one float4 load per row (16 B/lane, coalesced).
__global__ __launch_bounds__(128, 4)
void corner_pass1(const float* __restrict__ x, float* __restrict__ wsA,
                  float* __restrict__ wsBT) {
  const int t     = threadIdx.x;          // 0..127
  const int plane = blockIdx.y;           // 0..255
  const int jb    = blockIdx.x;           // 0..JBLK-1
  const int r0    = jb * RPB;

  const float4* base = (const float4*)(x + (size_t)plane * HH * WW + (size_t)r0 * WW);

  __shared__ float4 part[2][2];           // [row parity][wave] -> {T, M1, M2, _}
  __shared__ float  slotA[2], slotB[2];   // colsum-at-diagonal extracts

  float cs0 = 0.f, cs1 = 0.f, cs2 = 0.f, cs3 = 0.f;   // private column sums (cols 4t..4t+3)

  float4 v  = base[t];                    // row r0
  float4 v1 = base[128 + t];              // row r0+1
  const int wv  = t >> 6;
  const int l63 = ((t & 63) == 63);
  const int c0  = t << 2;                 // first column owned by this thread

  for (int rr = 0; rr < RPB; ++rr) {
    const int r = r0 + rr;
    const int q = 511 - r;

    float4 v2;                            // 2-deep prefetch
    if (rr + 2 < RPB) v2 = base[(rr + 2) * 128 + t];
    else              v2 = make_float4(0.f, 0.f, 0.f, 0.f);

    cs0 += v.x; cs1 += v.y; cs2 += v.z; cs3 += v.w;   // colsums now include row r

    const float p0 = v.x, p1 = p0 + v.y, p2 = p1 + v.z, p3 = p2 + v.w;

    const int lt1 = (r - 1) - c0;         // mask: cols <= r-1
    const int lt2 = q - c0;               // mask: cols <= 511-r
    float m1 = lt1 < 0 ? 0.f : (lt1 == 0 ? p0 : (lt1 == 1 ? p1 : (lt1 == 2 ? p2 : p3)));
    float m2 = lt2 < 0 ? 0.f : (lt2 == 0 ? p0 : (lt2 == 1 ? p1 : (lt2 == 2 ? p2 : p3)));
    float T  = p3;

    T  = wave_sum64(T);
    m1 = wave_sum64(m1);
    m2 = wave_sum64(m2);

    const int par = rr & 1;               // double-buffered slots: 1 barrier/row
    if (l63) part[par][wv] = make_float4(T, m1, m2, 0.f);

    if (t == (r >> 2)) {
      const int k = r & 3;
      slotA[par] = (k == 0 ? cs0 : k == 1 ? cs1 : k == 2 ? cs2 : cs3);
    }
    if (t == (q >> 2)) {
      const int k = q & 3;
      slotB[par] = (k == 0 ? cs0 : k == 1 ? cs1 : k == 2 ? cs2 : cs3);
    }

    __syncthreads();

    if (t == 0) {
      const float4 pa = part[par][0], pb = part[par][1];
      const float Ts = pa.x + pb.x;
      const float M1 = pa.y + pb.y;       // p(r-1)
      const float M2 = pa.z + pb.z;       // p(511-r)
      const float a  = slotA[par];        // local colsum incl r at col r
      const float b  = slotB[par];        // local colsum incl r at col q
      float4 A;
      A.x = M1 + a;                       // TL[r]  (+ prev[r] in pass 2)
      A.y = Ts - M2 + b;                  // TR[r]  (+ prev[q])
      A.z = M2 - b;                       // BL[q]  (+ tot[q] - prev[q])
      A.w = Ts - M1 - a;                  // BR[q]  (+ tot[r] - prev[r])
      ((float4*)wsA)[(size_t)plane * 512 + r] = A;
    }

    v = v1; v1 = v2;
  }

  // per-strip column totals (coalesced float4 store)
  float4* bt = (float4*)(wsBT + ((size_t)plane * JBLK + jb) * WW);
  bt[t] = make_float4(cs0, cs1, cs2, cs3);
}

// Kernel 2: cross-strip column-prefix fixup + count division + scatter to out.
// Tiny: ~14 MB traffic total.
__global__ __launch_bounds__(256)
void corner_pass2(const float* __restrict__ wsA, const float* __restrict__ wsBT,
                  float* __restrict__ out) {
  const int idx   = blockIdx.x * 256 + threadIdx.x;  // 0..131071
  const int plane = idx >> 9;
  const int r     = idx & 511;
  const int q     = 511 - r;

  const float4 A  = ((const float4*)wsA)[idx];
  const float* bt = wsBT + (size_t)plane * JBLK * 512;

  const int jb = r >> 6;  // strip containing row r (RPB = 64)
  float prev_r = 0.f, tot_r = 0.f, prev_q = 0.f, tot_q = 0.f;
#pragma unroll
  for (int jj = 0; jj < JBLK; ++jj) {
    const float br_ = bt[jj * 512 + r];
    const float bq_ = bt[jj * 512 + q];
    tot_r += br_; tot_q += bq_;
    if (jj < jb) { prev_r += br_; prev_q += bq_; }
  }

  const float TL = A.x + prev_r;
  const float TR = A.y + prev_q;
  const float BL = A.z + (tot_q - prev_q);
  const float BR = A.w + (tot_r - prev_r);

  const float invr = 1.0f / (float)(2 * r + 1);
  const float invq = 1.0f / (float)(2 * q + 1);

  const int b = plane >> 3, c = plane & 7;
  float* ob = out + (size_t)b * 512 * 32;
  ob[r * 32 + c]      = TL * invr;   // counts[i] = 2i+1
  ob[r * 32 + 8 + c]  = TR * invr;
  ob[q * 32 + 16 + c] = BL * invq;
  ob[q * 32 + 24 + c] = BR * invq;
}

extern "C" void kernel_launch(void* const* d_in, const int* in_sizes, int n_in,
                              void* d_out, int out_size, void* d_ws, size_t ws_size,
                              hipStream_t stream) {
  const float* x = (const float*)d_in[0];
  float* out = (float*)d_out;

  // workspace: wsA 2 MB (per-row float4), wsBT 4 MB (per-strip column totals)
  float* wsA  = (float*)d_ws;
  float* wsBT = wsA + (size_t)PLANES * 512 * 4;

  dim3 g1(JBLK, PLANES);
  corner_pass1<<<g1, 128, 0, stream>>>(x, wsA, wsBT);
  corner_pass2<<<512, 256, 0, stream>>>(wsA, wsBT, out);
}

// Round 2
// 366.616 us; speedup vs baseline: 1.0044x; 1.0044x over previous
//
#include <hip/hip_runtime.h>

// x[32,8,512,512] fp32 -> out[32,512,32] fp32. Element (r,w) belongs to one
// shell per corner: TL bin max(r,w), TR max(r,511-w), BL max(511-r,w),
// BR max(511-r,511-w). One streaming pass (268 MB) => roofline ~43 us.
//
// Identities (p(j)=prefix of row r, T=row total, colA[r]=col-r cumsum thru
// row r, colB[r]=same at col 511-r, total[c]=col totals):
//   TL[r]     = p(r-1)   + colA[r]
//   TR[r]     = T - p(511-r) + colB[r]
//   BL[511-r] = p(511-r) + total[511-r] - colB[r]
//   BR[511-r] = T - p(r-1) + total[r]   - colA[r]
//
// R1 lesson: per-row __syncthreads forced vmcnt(0) drain each row -> latency
// bound. This version: ONE WAVE OWNS A FULL ROW (64 lanes x 8 cols). All
// reductions are intra-wave (DPP + shfl). No barriers, no LDS -> the 4-deep
// register prefetch pipeline stays in flight.

#define PLANES 256   // B*C
#define WW     512
#define HH     512
#define JBLK   16    // row-strips per plane (one wave each)
#define RPB    32    // rows per strip
#define WPB    4     // waves per block (independent strips)
#define PF     4     // prefetch depth in rows

// Full 64-lane sum via DPP (VALU pipe). Result valid in lane 63.
__device__ __forceinline__ float wave_sum64(float v) {
  v += __int_as_float(__builtin_amdgcn_update_dpp(0, __float_as_int(v), 0x111, 0xf, 0xf, true)); // row_shr:1
  v += __int_as_float(__builtin_amdgcn_update_dpp(0, __float_as_int(v), 0x112, 0xf, 0xf, true)); // row_shr:2
  v += __int_as_float(__builtin_amdgcn_update_dpp(0, __float_as_int(v), 0x114, 0xf, 0xf, true)); // row_shr:4
  v += __int_as_float(__builtin_amdgcn_update_dpp(0, __float_as_int(v), 0x118, 0xf, 0xf, true)); // row_shr:8
  v += __int_as_float(__builtin_amdgcn_update_dpp(0, __float_as_int(v), 0x142, 0xf, 0xf, true)); // row_bcast:15
  v += __int_as_float(__builtin_amdgcn_update_dpp(0, __float_as_int(v), 0x143, 0xf, 0xf, true)); // row_bcast:31
  return v;
}

__global__ __launch_bounds__(256, 4)
void corner_pass1(const float* __restrict__ x, float* __restrict__ wsA,
                  float* __restrict__ wsBT) {
  const int t     = threadIdx.x;
  const int lane  = t & 63;
  const int wv    = t >> 6;
  const int plane = blockIdx.y;
  const int jb    = blockIdx.x * WPB + wv;   // this wave's strip
  const int r0    = jb * RPB;
  const int c0    = lane << 3;               // first of 8 owned columns

  const float4* base = (const float4*)(x + (size_t)plane * HH * WW + (size_t)r0 * WW);
  const int li = lane * 2;                   // float4 index of first owned half

  // register prefetch pipeline, PF rows deep (2 float4 per row per lane)
  float4 b0[PF], b1[PF];
#pragma unroll
  for (int i = 0; i < PF; ++i) {
    b0[i] = base[i * 128 + li];
    b1[i] = base[i * 128 + li + 1];
  }

  float cs[8] = {0.f, 0.f, 0.f, 0.f, 0.f, 0.f, 0.f, 0.f};  // private column sums

#pragma unroll 4
  for (int rr = 0; rr < RPB; ++rr) {
    const int r = r0 + rr;
    const int q = 511 - r;

    const float4 va = b0[rr & (PF - 1)];
    const float4 vb = b1[rr & (PF - 1)];
    if (rr + PF < RPB) {                     // wave-uniform branch (s_cbranch)
      b0[rr & (PF - 1)] = base[(rr + PF) * 128 + li];
      b1[rr & (PF - 1)] = base[(rr + PF) * 128 + li + 1];
    }

    // column sums now include row r
    cs[0] += va.x; cs[1] += va.y; cs[2] += va.z; cs[3] += va.w;
    cs[4] += vb.x; cs[5] += vb.y; cs[6] += vb.z; cs[7] += vb.w;

    // in-lane prefix of the 8 owned elements
    const float p0 = va.x, p1 = p0 + va.y, p2 = p1 + va.z, p3 = p2 + va.w;
    const float p4 = p3 + vb.x, p5 = p4 + vb.y, p6 = p5 + vb.z, p7 = p6 + vb.w;

    // masked sums: cols <= r-1 and cols <= 511-r (monotone select ladders)
    const int lt1 = (r - 1) - c0;
    const int lt2 = q - c0;
    float m1 = 0.f;
    m1 = (lt1 >= 0) ? p0 : m1; m1 = (lt1 >= 1) ? p1 : m1;
    m1 = (lt1 >= 2) ? p2 : m1; m1 = (lt1 >= 3) ? p3 : m1;
    m1 = (lt1 >= 4) ? p4 : m1; m1 = (lt1 >= 5) ? p5 : m1;
    m1 = (lt1 >= 6) ? p6 : m1; m1 = (lt1 >= 7) ? p7 : m1;
    float m2 = 0.f;
    m2 = (lt2 >= 0) ? p0 : m2; m2 = (lt2 >= 1) ? p1 : m2;
    m2 = (lt2 >= 2) ? p2 : m2; m2 = (lt2 >= 3) ? p3 : m2;
    m2 = (lt2 >= 4) ? p4 : m2; m2 = (lt2 >= 5) ? p5 : m2;
    m2 = (lt2 >= 6) ? p6 : m2; m2 = (lt2 >= 7) ? p7 : m2;

    float T = p7;
    T  = wave_sum64(T);                      // 3 independent DPP chains
    m1 = wave_sum64(m1);
    m2 = wave_sum64(m2);

    // diagonal column-sum extracts (incl. row r): col r and col q
    const int k1 = r & 7, k2 = q & 7;
    float selA = cs[0];
    selA = (k1 == 1) ? cs[1] : selA; selA = (k1 == 2) ? cs[2] : selA;
    selA = (k1 == 3) ? cs[3] : selA; selA = (k1 == 4) ? cs[4] : selA;
    selA = (k1 == 5) ? cs[5] : selA; selA = (k1 == 6) ? cs[6] : selA;
    selA = (k1 == 7) ? cs[7] : selA;
    float selB = cs[0];
    selB = (k2 == 1) ? cs[1] : selB; selB = (k2 == 2) ? cs[2] : selB;
    selB = (k2 == 3) ? cs[3] : selB; selB = (k2 == 4) ? cs[4] : selB;
    selB = (k2 == 5) ? cs[5] : selB; selB = (k2 == 7) ? cs[7] : selB;
    selB = (k2 == 6) ? cs[6] : selB;

    const float a = __shfl(selA, r >> 3, 64);  // ds_bpermute, no barrier
    const float b = __shfl(selB, q >> 3, 64);

    if (lane == 63) {                        // T,m1,m2 valid in lane 63
      float4 A;
      A.x = m1 + a;                          // TL[r]  (+ prev[r] in pass 2)
      A.y = T - m2 + b;                      // TR[r]  (+ prev[q])
      A.z = m2 - b;                          // BL[q]  (+ tot[q] - prev[q])
      A.w = T - m1 - a;                      // BR[q]  (+ tot[r] - prev[r])
      ((float4*)wsA)[(size_t)plane * 512 + r] = A;
    }
  }

  // per-strip column totals: lane's 8 contiguous cols -> two float4 stores
  float4* bt = (float4*)(wsBT + ((size_t)plane * JBLK + jb) * WW + c0);
  bt[0] = make_float4(cs[0], cs[1], cs[2], cs[3]);
  bt[1] = make_float4(cs[4], cs[5], cs[6], cs[7]);
}

// Pass 2: cross-strip column-prefix fixup + count division + scatter to out.
__global__ __launch_bounds__(256)
void corner_pass2(const float* __restrict__ wsA, const float* __restrict__ wsBT,
                  float* __restrict__ out) {
  const int idx   = blockIdx.x * 256 + threadIdx.x;  // 0..131071
  const int plane = idx >> 9;
  const int r     = idx & 511;
  const int q     = 511 - r;

  const float4 A  = ((const float4*)wsA)[idx];
  const float* bt = wsBT + (size_t)plane * JBLK * 512;

  const int jb = r >> 5;  // strip containing row r (RPB = 32)
  float prev_r = 0.f, tot_r = 0.f, prev_q = 0.f, tot_q = 0.f;
#pragma unroll
  for (int jj = 0; jj < JBLK; ++jj) {
    const float br_ = bt[jj * 512 + r];
    const float bq_ = bt[jj * 512 + q];
    tot_r += br_; tot_q += bq_;
    if (jj < jb) { prev_r += br_; prev_q += bq_; }
  }

  const float TL = A.x + prev_r;
  const float TR = A.y + prev_q;
  const float BL = A.z + (tot_q - prev_q);
  const float BR = A.w + (tot_r - prev_r);

  const float invr = 1.0f / (float)(2 * r + 1);
  const float invq = 1.0f / (float)(2 * q + 1);

  const int b = plane >> 3, c = plane & 7;
  float* ob = out + (size_t)b * 512 * 32;
  ob[r * 32 + c]      = TL * invr;   // counts[i] = 2i+1
  ob[r * 32 + 8 + c]  = TR * invr;
  ob[q * 32 + 16 + c] = BL * invq;
  ob[q * 32 + 24 + c] = BR * invq;
}

extern "C" void kernel_launch(void* const* d_in, const int* in_sizes, int n_in,
                              void* d_out, int out_size, void* d_ws, size_t ws_size,
                              hipStream_t stream) {
  const float* x = (const float*)d_in[0];
  float* out = (float*)d_out;

  // ws layout: wsA 2 MB (per-row float4), wsBT 8 MB (per-strip column totals)
  float* wsA  = (float*)d_ws;
  float* wsBT = wsA + (size_t)PLANES * 512 * 4;

  dim3 g1(JBLK / WPB, PLANES);               // 4 x 256 blocks, 4 waves each
  corner_pass1<<<g1, 256, 0, stream>>>(x, wsA, wsBT);
  corner_pass2<<<512, 256, 0, stream>>>(wsA, wsBT, out);
}